// Round 1
// baseline (2954.886 us; speedup 1.0000x reference)
//
#include <hip/hip_runtime.h>
#include <hip/hip_bf16.h>

// VGAE GCN encoder, fused:
//   Hs = (x @ [W_mu|W_ls]) * dinv[row]        (GEMM + source-side norm)
//   agg = Hs (self-loop init); agg[dst] += Hs[src] over E edges (atomics)
//   z = (dinv*agg_mu + b_mu) + eps * exp(min(dinv*agg_ls + b_ls, 10))
//
// ws layout: deg[N] int | Hs[N*128] f32 | agg_ls[N*64] f32  (~77.2 MB)
// agg_mu lives in d_out (finalize rewrites it in place).

#define CIN  128
#define CCAT 128
#define COUT 64
#define MAX_LOGSTD 10.0f

#define TILE_M 128
#define KCHUNK 32
#define LDS_STRIDE 132   // pad: bank = (4k + idx) % 32; breaks row-stride conflicts

// ---------------- degree count (real edges only; +1 self-loop added later) --
__global__ __launch_bounds__(256) void deg_count_kernel(
    const int* __restrict__ dst, int* __restrict__ deg, int E)
{
    int i = blockIdx.x * blockDim.x + threadIdx.x;
    if (i < E) atomicAdd(&deg[dst[i]], 1);
}

// ---------------- GEMM: H = x @ [Wmu|Wls], scaled by dinv, + agg init ------
// 128x128 tile per 256-thread block, 8x8 register tile per thread,
// K staged in 32-chunks (x transposed in LDS for outer-product reads).
__global__ __launch_bounds__(256) void gemm_scale_kernel(
    const float* __restrict__ x,
    const float* __restrict__ Wmu,
    const float* __restrict__ Wls,
    const int*   __restrict__ deg,
    float* __restrict__ Hs,
    float* __restrict__ aggmu,   // = d_out, [N,64]
    float* __restrict__ aggls,   // [N,64]
    int N)
{
    __shared__ float xs [KCHUNK * LDS_STRIDE];  // [k][row]  (transposed)
    __shared__ float wsl[KCHUNK * LDS_STRIDE];  // [k][col]

    const int t    = threadIdx.x;
    const int row0 = blockIdx.x * TILE_M;
    const int c0   = (t & 15) * 8;   // col group: 16 groups x 8 cols = 128
    const int r0   = (t >> 4) * 8;   // row group: 16 groups x 8 rows = 128

    float acc[8][8];
    #pragma unroll
    for (int i = 0; i < 8; ++i)
        #pragma unroll
        for (int j = 0; j < 8; ++j) acc[i][j] = 0.f;

    for (int k0 = 0; k0 < CIN; k0 += KCHUNK) {
        // stage x chunk transposed: xs[k][row] = x[row0+row][k0+k]
        #pragma unroll
        for (int it = 0; it < 4; ++it) {
            int idx = it * 256 + t;       // 0..1023 = 128 rows * 8 float4
            int row = idx >> 3;
            int q   = idx & 7;            // float4 index in the 32-wide K chunk
            int grow = row0 + row;
            float4 v = make_float4(0.f, 0.f, 0.f, 0.f);
            if (grow < N)
                v = *(const float4*)&x[(size_t)grow * CIN + k0 + q * 4];
            xs[(q*4+0)*LDS_STRIDE + row] = v.x;
            xs[(q*4+1)*LDS_STRIDE + row] = v.y;
            xs[(q*4+2)*LDS_STRIDE + row] = v.z;
            xs[(q*4+3)*LDS_STRIDE + row] = v.w;
        }
        // stage W chunk: wsl[k][c] with c<64 from Wmu, c>=64 from Wls
        #pragma unroll
        for (int it = 0; it < 4; ++it) {
            int idx = it * 256 + t;       // 0..1023 = 32 k * 32 float4
            int k   = idx >> 5;
            int q   = idx & 31;
            float4 v;
            if (q < 16) v = *(const float4*)&Wmu[(size_t)(k0 + k) * COUT + q * 4];
            else        v = *(const float4*)&Wls[(size_t)(k0 + k) * COUT + (q - 16) * 4];
            *(float4*)&wsl[k * LDS_STRIDE + q * 4] = v;
        }
        __syncthreads();

        #pragma unroll
        for (int k = 0; k < KCHUNK; ++k) {
            const float* xr = &xs [k * LDS_STRIDE + r0];
            const float* wr = &wsl[k * LDS_STRIDE + c0];
            float a[8], b[8];
            *(float4*)&a[0] = *(const float4*)&xr[0];
            *(float4*)&a[4] = *(const float4*)&xr[4];
            *(float4*)&b[0] = *(const float4*)&wr[0];
            *(float4*)&b[4] = *(const float4*)&wr[4];
            #pragma unroll
            for (int i = 0; i < 8; ++i)
                #pragma unroll
                for (int j = 0; j < 8; ++j)
                    acc[i][j] = fmaf(a[i], b[j], acc[i][j]);
        }
        __syncthreads();
    }

    // epilogue: scale by dinv[row], write Hs + init agg (self-loop term)
    #pragma unroll
    for (int i = 0; i < 8; ++i) {
        int grow = row0 + r0 + i;
        if (grow < N) {
            float dinv = rsqrtf((float)(deg[grow] + 1));
            float4 v0, v1;
            v0.x = acc[i][0] * dinv; v0.y = acc[i][1] * dinv;
            v0.z = acc[i][2] * dinv; v0.w = acc[i][3] * dinv;
            v1.x = acc[i][4] * dinv; v1.y = acc[i][5] * dinv;
            v1.z = acc[i][6] * dinv; v1.w = acc[i][7] * dinv;
            *(float4*)&Hs[(size_t)grow * CCAT + c0]     = v0;
            *(float4*)&Hs[(size_t)grow * CCAT + c0 + 4] = v1;
            if (c0 < 64) {
                *(float4*)&aggmu[(size_t)grow * COUT + c0]     = v0;
                *(float4*)&aggmu[(size_t)grow * COUT + c0 + 4] = v1;
            } else {
                *(float4*)&aggls[(size_t)grow * COUT + (c0 - 64)]     = v0;
                *(float4*)&aggls[(size_t)grow * COUT + (c0 - 64) + 4] = v1;
            }
        }
    }
}

// ---------------- edge scatter: agg[dst] += Hs[src] ------------------------
// 32 threads per edge, one float4 (4 channels) + 4 fp32 atomics per thread.
__global__ __launch_bounds__(256) void scatter_kernel(
    const int* __restrict__ src, const int* __restrict__ dst,
    const float* __restrict__ Hs,
    float* __restrict__ aggmu, float* __restrict__ aggls, int E)
{
    long gid = (long)blockIdx.x * 256 + threadIdx.x;
    int e = (int)(gid >> 5);
    if (e >= E) return;
    int c = (int)(gid & 31) * 4;
    int s = src[e], d = dst[e];
    float4 v = *(const float4*)&Hs[(size_t)s * CCAT + c];
    float* p = (c < 64) ? &aggmu[(size_t)d * COUT + c]
                        : &aggls[(size_t)d * COUT + (c - 64)];
    atomicAdd(p + 0, v.x);
    atomicAdd(p + 1, v.y);
    atomicAdd(p + 2, v.z);
    atomicAdd(p + 3, v.w);
}

// ---------------- finalize: z = mu + eps*exp(min(logstd, 10)) --------------
__global__ __launch_bounds__(256) void finalize_kernel(
    const int*   __restrict__ deg,
    const float* __restrict__ bmu, const float* __restrict__ bls,
    const float* __restrict__ eps,
    const float* __restrict__ aggls,
    float* __restrict__ out,   // in: agg_mu, out: z (in place)
    int N)
{
    long gid = (long)blockIdx.x * 256 + threadIdx.x;
    int i = (int)(gid >> 4);
    if (i >= N) return;
    int c = (int)(gid & 15) * 4;
    float dinv = rsqrtf((float)(deg[i] + 1));
    float4 amu = *(const float4*)&out  [(size_t)i * COUT + c];
    float4 als = *(const float4*)&aggls[(size_t)i * COUT + c];
    float4 e4  = *(const float4*)&eps  [(size_t)i * COUT + c];
    float4 bm  = *(const float4*)&bmu[c];
    float4 bl  = *(const float4*)&bls[c];
    float4 z;
    z.x = (dinv * amu.x + bm.x) + e4.x * expf(fminf(dinv * als.x + bl.x, MAX_LOGSTD));
    z.y = (dinv * amu.y + bm.y) + e4.y * expf(fminf(dinv * als.y + bl.y, MAX_LOGSTD));
    z.z = (dinv * amu.z + bm.z) + e4.z * expf(fminf(dinv * als.z + bl.z, MAX_LOGSTD));
    z.w = (dinv * amu.w + bm.w) + e4.w * expf(fminf(dinv * als.w + bl.w, MAX_LOGSTD));
    *(float4*)&out[(size_t)i * COUT + c] = z;
}

extern "C" void kernel_launch(void* const* d_in, const int* in_sizes, int n_in,
                              void* d_out, int out_size, void* d_ws, size_t ws_size,
                              hipStream_t stream) {
    const float* x   = (const float*)d_in[0];
    const int*   ei  = (const int*)  d_in[1];   // [2, E] int32
    const float* Wmu = (const float*)d_in[2];
    const float* bmu = (const float*)d_in[3];
    const float* Wls = (const float*)d_in[4];
    const float* bls = (const float*)d_in[5];
    const float* eps = (const float*)d_in[6];

    const int E = in_sizes[1] / 2;
    const int N = in_sizes[6] / COUT;

    const int* src = ei;
    const int* dst = ei + E;

    // workspace carve-up
    char*  ws    = (char*)d_ws;
    int*   deg   = (int*)ws;
    size_t off   = (((size_t)N * sizeof(int)) + 255) & ~(size_t)255;
    float* Hs    = (float*)(ws + off);
    off         += (size_t)N * CCAT * sizeof(float);
    float* aggls = (float*)(ws + off);
    float* aggmu = (float*)d_out;

    hipMemsetAsync(deg, 0, (size_t)N * sizeof(int), stream);

    deg_count_kernel<<<(E + 255) / 256, 256, 0, stream>>>(dst, deg, E);

    gemm_scale_kernel<<<(N + TILE_M - 1) / TILE_M, 256, 0, stream>>>(
        x, Wmu, Wls, deg, Hs, aggmu, aggls, N);

    long sthreads = (long)E * 32;
    scatter_kernel<<<(int)((sthreads + 255) / 256), 256, 0, stream>>>(
        src, dst, Hs, aggmu, aggls, E);

    finalize_kernel<<<(int)(((long)N * 16 + 255) / 256), 256, 0, stream>>>(
        deg, bmu, bls, eps, aggls, (float*)d_out, N);
}

// Round 2
// 474.826 us; speedup vs baseline: 6.2231x; 6.2231x over previous
//
#include <hip/hip_runtime.h>
#include <hip/hip_bf16.h>

// VGAE GCN encoder, pull-based (no fp32 atomics):
//   deg = in-degree(dst);  rowptr = exclusive_scan(deg);  csr = counting-sort(src by dst)
//   Hs = (x @ [W_mu|W_ls]) * dinv[row]                     (GEMM + source-side norm)
//   per node d (one wave): acc = Hs[d] + sum_{s in csr row d} Hs[s]
//   z = (dinv_d*acc_mu + b_mu) + eps * exp(min(dinv_d*acc_ls + b_ls, 10))
//
// ws: deg[N] | rowptr[N+1] | cursor[N] | bsums[256] | boffs[256] | csr[E] | Hs[N*128]
//   ~59 MB (fits; R1 used 77 MB).

#define CIN  128
#define CCAT 128
#define COUT 64
#define MAX_LOGSTD 10.0f

#define TILE_M 128
#define KCHUNK 32
#define LDS_STRIDE 132

// ---------------- degree count (real in-edges; self-loop handled later) ----
__global__ __launch_bounds__(256) void deg_count_kernel(
    const int* __restrict__ dst, int* __restrict__ deg, int E)
{
    int i = blockIdx.x * blockDim.x + threadIdx.x;
    if (i < E) atomicAdd(&deg[dst[i]], 1);
}

// ---------------- scan stage 1: per-block (1024 elems) exclusive scan ------
__global__ __launch_bounds__(256) void scan_block_kernel(
    const int* __restrict__ deg, int* __restrict__ rowptr,
    int* __restrict__ bsums, int N)
{
    __shared__ int sdata[256];
    const int t = threadIdx.x;
    const int base = blockIdx.x * 1024 + t * 4;
    int d0 = (base + 0 < N) ? deg[base + 0] : 0;
    int d1 = (base + 1 < N) ? deg[base + 1] : 0;
    int d2 = (base + 2 < N) ? deg[base + 2] : 0;
    int d3 = (base + 3 < N) ? deg[base + 3] : 0;
    int tsum = d0 + d1 + d2 + d3;
    sdata[t] = tsum;
    __syncthreads();
    for (int off = 1; off < 256; off <<= 1) {
        int v = (t >= off) ? sdata[t - off] : 0;
        __syncthreads();
        sdata[t] += v;
        __syncthreads();
    }
    int excl = sdata[t] - tsum;            // exclusive prefix of this thread
    if (base + 0 < N) rowptr[base + 0] = excl;
    if (base + 1 < N) rowptr[base + 1] = excl + d0;
    if (base + 2 < N) rowptr[base + 2] = excl + d0 + d1;
    if (base + 3 < N) rowptr[base + 3] = excl + d0 + d1 + d2;
    if (t == 255) bsums[blockIdx.x] = sdata[255];
}

// ---------------- scan stage 2: scan of block sums (nb <= 256) -------------
__global__ __launch_bounds__(256) void scan_top_kernel(
    const int* __restrict__ bsums, int* __restrict__ boffs, int nb)
{
    __shared__ int sdata[256];
    const int t = threadIdx.x;
    int v0 = (t < nb) ? bsums[t] : 0;
    sdata[t] = v0;
    __syncthreads();
    for (int off = 1; off < 256; off <<= 1) {
        int v = (t >= off) ? sdata[t - off] : 0;
        __syncthreads();
        sdata[t] += v;
        __syncthreads();
    }
    boffs[t] = sdata[t] - v0;              // exclusive
}

// ---------------- scan stage 3: add block offsets, init cursor -------------
__global__ __launch_bounds__(256) void add_off_kernel(
    int* __restrict__ rowptr, int* __restrict__ cursor,
    const int* __restrict__ boffs, int N, int E)
{
    int i = blockIdx.x * blockDim.x + threadIdx.x;
    if (i < N) {
        int r = rowptr[i] + boffs[i >> 10];
        rowptr[i] = r;
        cursor[i] = r;
    }
    if (i == 0) rowptr[N] = E;
}

// ---------------- CSR fill: counting-sort placement ------------------------
__global__ __launch_bounds__(256) void fill_kernel(
    const int* __restrict__ src, const int* __restrict__ dst,
    int* __restrict__ cursor, int* __restrict__ csr, int E)
{
    int e = blockIdx.x * blockDim.x + threadIdx.x;
    if (e < E) {
        int pos = atomicAdd(&cursor[dst[e]], 1);
        csr[pos] = src[e];
    }
}

// ---------------- GEMM: Hs = (x @ [Wmu|Wls]) * dinv[row] -------------------
__global__ __launch_bounds__(256) void gemm_scale_kernel(
    const float* __restrict__ x,
    const float* __restrict__ Wmu,
    const float* __restrict__ Wls,
    const int*   __restrict__ deg,
    float* __restrict__ Hs,
    int N)
{
    __shared__ float xs [KCHUNK * LDS_STRIDE];  // [k][row] (transposed)
    __shared__ float wsl[KCHUNK * LDS_STRIDE];  // [k][col]

    const int t    = threadIdx.x;
    const int row0 = blockIdx.x * TILE_M;
    const int c0   = (t & 15) * 8;
    const int r0   = (t >> 4) * 8;

    float acc[8][8];
    #pragma unroll
    for (int i = 0; i < 8; ++i)
        #pragma unroll
        for (int j = 0; j < 8; ++j) acc[i][j] = 0.f;

    for (int k0 = 0; k0 < CIN; k0 += KCHUNK) {
        #pragma unroll
        for (int it = 0; it < 4; ++it) {
            int idx = it * 256 + t;
            int row = idx >> 3;
            int q   = idx & 7;
            int grow = row0 + row;
            float4 v = make_float4(0.f, 0.f, 0.f, 0.f);
            if (grow < N)
                v = *(const float4*)&x[(size_t)grow * CIN + k0 + q * 4];
            xs[(q*4+0)*LDS_STRIDE + row] = v.x;
            xs[(q*4+1)*LDS_STRIDE + row] = v.y;
            xs[(q*4+2)*LDS_STRIDE + row] = v.z;
            xs[(q*4+3)*LDS_STRIDE + row] = v.w;
        }
        #pragma unroll
        for (int it = 0; it < 4; ++it) {
            int idx = it * 256 + t;
            int k   = idx >> 5;
            int q   = idx & 31;
            float4 v;
            if (q < 16) v = *(const float4*)&Wmu[(size_t)(k0 + k) * COUT + q * 4];
            else        v = *(const float4*)&Wls[(size_t)(k0 + k) * COUT + (q - 16) * 4];
            *(float4*)&wsl[k * LDS_STRIDE + q * 4] = v;
        }
        __syncthreads();

        #pragma unroll
        for (int k = 0; k < KCHUNK; ++k) {
            const float* xr = &xs [k * LDS_STRIDE + r0];
            const float* wr = &wsl[k * LDS_STRIDE + c0];
            float a[8], b[8];
            *(float4*)&a[0] = *(const float4*)&xr[0];
            *(float4*)&a[4] = *(const float4*)&xr[4];
            *(float4*)&b[0] = *(const float4*)&wr[0];
            *(float4*)&b[4] = *(const float4*)&wr[4];
            #pragma unroll
            for (int i = 0; i < 8; ++i)
                #pragma unroll
                for (int j = 0; j < 8; ++j)
                    acc[i][j] = fmaf(a[i], b[j], acc[i][j]);
        }
        __syncthreads();
    }

    #pragma unroll
    for (int i = 0; i < 8; ++i) {
        int grow = row0 + r0 + i;
        if (grow < N) {
            float dinv = rsqrtf((float)(deg[grow] + 1));
            float4 v0, v1;
            v0.x = acc[i][0] * dinv; v0.y = acc[i][1] * dinv;
            v0.z = acc[i][2] * dinv; v0.w = acc[i][3] * dinv;
            v1.x = acc[i][4] * dinv; v1.y = acc[i][5] * dinv;
            v1.z = acc[i][6] * dinv; v1.w = acc[i][7] * dinv;
            *(float4*)&Hs[(size_t)grow * CCAT + c0]     = v0;
            *(float4*)&Hs[(size_t)grow * CCAT + c0 + 4] = v1;
        }
    }
}

// ---------------- gather + finalize: one wave per node ---------------------
// lane l holds channels {2l, 2l+1} of the 128-wide concat (mu: lanes 0-31,
// ls: lanes 32-63). After reduction, shfl_xor(32) pairs mu with ls.
__global__ __launch_bounds__(256) void gather_finalize_kernel(
    const int*   __restrict__ rowptr,
    const int*   __restrict__ csr,
    const float* __restrict__ Hs,
    const float* __restrict__ bmu, const float* __restrict__ bls,
    const float* __restrict__ eps,
    float* __restrict__ out, int N)
{
    const int t    = threadIdx.x;
    const int lane = t & 63;
    const int node = blockIdx.x * 4 + (t >> 6);
    if (node >= N) return;

    const float2* Hs2 = (const float2*)Hs;
    const int begin = rowptr[node];
    const int end   = rowptr[node + 1];

    // self-loop init
    float2 acc = Hs2[(size_t)node * 64 + lane];

    for (int base = begin; base < end; base += 64) {
        int navail = end - base;
        if (navail > 64) navail = 64;
        int sv = (lane < navail) ? csr[base + lane] : 0;
        int j = 0;
        for (; j + 4 <= navail; j += 4) {
            int s0 = __shfl(sv, j,     64);
            int s1 = __shfl(sv, j + 1, 64);
            int s2 = __shfl(sv, j + 2, 64);
            int s3 = __shfl(sv, j + 3, 64);
            float2 v0 = Hs2[(size_t)s0 * 64 + lane];
            float2 v1 = Hs2[(size_t)s1 * 64 + lane];
            float2 v2 = Hs2[(size_t)s2 * 64 + lane];
            float2 v3 = Hs2[(size_t)s3 * 64 + lane];
            acc.x += (v0.x + v1.x) + (v2.x + v3.x);
            acc.y += (v0.y + v1.y) + (v2.y + v3.y);
        }
        for (; j < navail; ++j) {
            int s = __shfl(sv, j, 64);
            float2 v = Hs2[(size_t)s * 64 + lane];
            acc.x += v.x;
            acc.y += v.y;
        }
    }

    // exchange mu/ls halves: lane l (<32) gets ls channels {2l,2l+1} from l+32
    float ox = __shfl_xor(acc.x, 32, 64);
    float oy = __shfl_xor(acc.y, 32, 64);

    if (lane < 32) {
        float dinv = rsqrtf((float)(end - begin + 1));
        const float2* bmu2 = (const float2*)bmu;
        const float2* bls2 = (const float2*)bls;
        float2 bm = bmu2[lane];
        float2 bl = bls2[lane];
        float2 e2 = ((const float2*)eps)[(size_t)node * 32 + lane];
        float mu0 = acc.x * dinv + bm.x;
        float mu1 = acc.y * dinv + bm.y;
        float ls0 = ox * dinv + bl.x;
        float ls1 = oy * dinv + bl.y;
        float2 z;
        z.x = mu0 + e2.x * expf(fminf(ls0, MAX_LOGSTD));
        z.y = mu1 + e2.y * expf(fminf(ls1, MAX_LOGSTD));
        ((float2*)out)[(size_t)node * 32 + lane] = z;
    }
}

extern "C" void kernel_launch(void* const* d_in, const int* in_sizes, int n_in,
                              void* d_out, int out_size, void* d_ws, size_t ws_size,
                              hipStream_t stream) {
    const float* x   = (const float*)d_in[0];
    const int*   ei  = (const int*)  d_in[1];   // [2, E] int32
    const float* Wmu = (const float*)d_in[2];
    const float* bmu = (const float*)d_in[3];
    const float* Wls = (const float*)d_in[4];
    const float* bls = (const float*)d_in[5];
    const float* eps = (const float*)d_in[6];

    const int E = in_sizes[1] / 2;
    const int N = in_sizes[6] / COUT;

    const int* src = ei;
    const int* dst = ei + E;

    // workspace carve-up (all 512B-aligned)
    char* ws = (char*)d_ws;
    size_t off = 0;
    auto carve = [&](size_t bytes) {
        char* p = ws + off;
        off = (off + bytes + 511) & ~(size_t)511;
        return p;
    };
    int* deg    = (int*)carve((size_t)N * sizeof(int));
    int* rowptr = (int*)carve((size_t)(N + 1) * sizeof(int));
    int* cursor = (int*)carve((size_t)N * sizeof(int));
    int* bsums  = (int*)carve(256 * sizeof(int));
    int* boffs  = (int*)carve(256 * sizeof(int));
    int* csr    = (int*)carve((size_t)E * sizeof(int));
    float* Hs   = (float*)carve((size_t)N * CCAT * sizeof(float));

    const int nb = (N + 1023) / 1024;   // blocks in scan stage 1 (<=256)

    hipMemsetAsync(deg, 0, (size_t)N * sizeof(int), stream);

    deg_count_kernel<<<(E + 255) / 256, 256, 0, stream>>>(dst, deg, E);
    scan_block_kernel<<<nb, 256, 0, stream>>>(deg, rowptr, bsums, N);
    scan_top_kernel<<<1, 256, 0, stream>>>(bsums, boffs, nb);
    add_off_kernel<<<(N + 255) / 256, 256, 0, stream>>>(rowptr, cursor, boffs, N, E);
    fill_kernel<<<(E + 255) / 256, 256, 0, stream>>>(src, dst, cursor, csr, E);

    gemm_scale_kernel<<<(N + TILE_M - 1) / TILE_M, 256, 0, stream>>>(
        x, Wmu, Wls, deg, Hs, N);

    gather_finalize_kernel<<<(N + 3) / 4, 256, 0, stream>>>(
        rowptr, csr, Hs, bmu, bls, eps, (float*)d_out, N);
}

// Round 3
// 310.348 us; speedup vs baseline: 9.5212x; 1.5300x over previous
//
#include <hip/hip_runtime.h>
#include <hip/hip_bf16.h>
#include <hip/hip_fp16.h>

// VGAE GCN encoder, pull-based, atomic-free CSR build:
//   two-level bucket sort of edges by dst (128-node buckets, LDS-ranked),
//   rowptr emitted directly from per-bucket histograms.
//   Hs = (x @ [W_mu|W_ls]) * dinv[row]  stored fp16  (GEMM + source-side norm)
//   per node d (one wave): acc = Hs[d] + sum_{s in csr row d} Hs[s]
//   z = (dinv_d*acc_mu + b_mu) + eps * exp(min(dinv_d*acc_ls + b_ls, 10))

#define CIN  128
#define CCAT 128
#define COUT 64
#define MAX_LOGSTD 10.0f

#define TILE_M 128
#define KCHUNK 32
#define LDS_STRIDE 132

#define BSHIFT 7               // 128 nodes per bucket
#define PART_G 128             // partition grid (blocks)
#define SORT_CAP 3072          // LDS staging capacity per bucket (avg ~1563)

// ---------------- pass 1: per-block coarse histogram (LDS atomics only) ----
__global__ __launch_bounds__(256) void hist_kernel(
    const int* __restrict__ dst, int* __restrict__ bh,
    int E, int NB, int chunk)
{
    __shared__ int h[1024];
    const int t = threadIdx.x, g = blockIdx.x;
    for (int i = t; i < NB; i += 256) h[i] = 0;
    __syncthreads();
    const int lo = g * chunk;
    const int hi = min(E, lo + chunk);
    for (int e = lo + t; e < hi; e += 256)
        atomicAdd(&h[dst[e] >> BSHIFT], 1);
    __syncthreads();
    for (int b = t; b < NB; b += 256) bh[(size_t)b * PART_G + g] = h[b];
}

// ---------------- scan stage 1: per-block (1024 elems) exclusive scan ------
__global__ __launch_bounds__(256) void scan_block_kernel(
    const int* __restrict__ in, int* __restrict__ out,
    int* __restrict__ bsums, int M)
{
    __shared__ int sdata[256];
    const int t = threadIdx.x;
    const int base = blockIdx.x * 1024 + t * 4;
    int d0 = (base + 0 < M) ? in[base + 0] : 0;
    int d1 = (base + 1 < M) ? in[base + 1] : 0;
    int d2 = (base + 2 < M) ? in[base + 2] : 0;
    int d3 = (base + 3 < M) ? in[base + 3] : 0;
    int tsum = d0 + d1 + d2 + d3;
    sdata[t] = tsum;
    __syncthreads();
    for (int off = 1; off < 256; off <<= 1) {
        int v = (t >= off) ? sdata[t - off] : 0;
        __syncthreads();
        sdata[t] += v;
        __syncthreads();
    }
    int excl = sdata[t] - tsum;
    if (base + 0 < M) out[base + 0] = excl;
    if (base + 1 < M) out[base + 1] = excl + d0;
    if (base + 2 < M) out[base + 2] = excl + d0 + d1;
    if (base + 3 < M) out[base + 3] = excl + d0 + d1 + d2;
    if (t == 255) bsums[blockIdx.x] = sdata[255];
}

// ---------------- scan stage 2: scan of block sums (nb <= 256) -------------
__global__ __launch_bounds__(256) void scan_top_kernel(
    const int* __restrict__ bsums, int* __restrict__ boffs, int nb)
{
    __shared__ int sdata[256];
    const int t = threadIdx.x;
    int v0 = (t < nb) ? bsums[t] : 0;
    sdata[t] = v0;
    __syncthreads();
    for (int off = 1; off < 256; off <<= 1) {
        int v = (t >= off) ? sdata[t - off] : 0;
        __syncthreads();
        sdata[t] += v;
        __syncthreads();
    }
    boffs[t] = sdata[t] - v0;
}

// ---------------- scan stage 3: add block offsets --------------------------
__global__ __launch_bounds__(256) void add_off_kernel(
    int* __restrict__ sc, const int* __restrict__ boffs, int M)
{
    int i = blockIdx.x * blockDim.x + threadIdx.x;
    if (i < M) sc[i] += boffs[i >> 10];
}

// ---------------- pass 2: partition edges into bucket-contiguous pairs -----
// block g's range for bucket b is [sc[b*G+g], sc[b*G+g]+count) -- exact, so
// LDS cursors suffice (no global atomics).
__global__ __launch_bounds__(256) void partition_kernel(
    const int* __restrict__ src, const int* __restrict__ dst,
    const int* __restrict__ sc, int2* __restrict__ pairs,
    int E, int NB, int chunk)
{
    __shared__ int lcur[1024];
    const int t = threadIdx.x, g = blockIdx.x;
    for (int b = t; b < NB; b += 256) lcur[b] = sc[(size_t)b * PART_G + g];
    __syncthreads();
    const int lo = g * chunk;
    const int hi = min(E, lo + chunk);
    for (int e = lo + t; e < hi; e += 256) {
        int d = dst[e], s = src[e];
        int pos = atomicAdd(&lcur[d >> BSHIFT], 1);
        pairs[pos] = make_int2(d, s);
    }
}

// ---------------- pass 3: sort each bucket in LDS, emit csr + rowptr -------
__global__ __launch_bounds__(256) void bucket_sort_kernel(
    const int* __restrict__ sc, const int2* __restrict__ pairs,
    int* __restrict__ csr, int* __restrict__ rowptr,
    int E, int NB, int N)
{
    __shared__ int hist[128];
    __shared__ int scs[128];
    __shared__ int cur[128];
    __shared__ int ssort[SORT_CAP];
    const int t = threadIdx.x, b = blockIdx.x;
    const int begin = sc[(size_t)b * PART_G];
    const int end   = (b == NB - 1) ? E : sc[(size_t)(b + 1) * PART_G];
    const int cnt   = end - begin;

    if (t < 128) hist[t] = 0;
    __syncthreads();
    for (int i = t; i < cnt; i += 256)
        atomicAdd(&hist[pairs[begin + i].x & 127], 1);
    __syncthreads();
    // inclusive scan of 128 bins (Hillis-Steele in LDS)
    if (t < 128) scs[t] = hist[t];
    __syncthreads();
    for (int off = 1; off < 128; off <<= 1) {
        int v = (t < 128 && t >= off) ? scs[t - off] : 0;
        __syncthreads();
        if (t < 128) scs[t] += v;
        __syncthreads();
    }
    if (t < 128) {
        int ex = scs[t] - hist[t];
        cur[t] = ex;
        int node = (b << BSHIFT) + t;
        if (node <= N) rowptr[node] = begin + ex;
    }
    if (b == NB - 1 && t == 255) rowptr[N] = E;  // benign same-value overlap
    __syncthreads();

    const bool in_lds = (cnt <= SORT_CAP);
    for (int i = t; i < cnt; i += 256) {
        int2 p = pairs[begin + i];
        int pos = atomicAdd(&cur[p.x & 127], 1);
        if (in_lds) ssort[pos] = p.y;
        else        csr[begin + pos] = p.y;   // rare fallback
    }
    __syncthreads();
    if (in_lds)
        for (int i = t; i < cnt; i += 256) csr[begin + i] = ssort[i];
}

// ---------------- GEMM: Hs = fp16((x @ [Wmu|Wls]) * dinv[row]) -------------
__global__ __launch_bounds__(256) void gemm_scale_kernel(
    const float* __restrict__ x,
    const float* __restrict__ Wmu,
    const float* __restrict__ Wls,
    const int*   __restrict__ rowptr,
    __half* __restrict__ Hs,
    int N)
{
    __shared__ float xs [KCHUNK * LDS_STRIDE];  // [k][row] (transposed)
    __shared__ float wsl[KCHUNK * LDS_STRIDE];  // [k][col]

    const int t    = threadIdx.x;
    const int row0 = blockIdx.x * TILE_M;
    const int c0   = (t & 15) * 8;
    const int r0   = (t >> 4) * 8;

    float acc[8][8];
    #pragma unroll
    for (int i = 0; i < 8; ++i)
        #pragma unroll
        for (int j = 0; j < 8; ++j) acc[i][j] = 0.f;

    for (int k0 = 0; k0 < CIN; k0 += KCHUNK) {
        #pragma unroll
        for (int it = 0; it < 4; ++it) {
            int idx = it * 256 + t;
            int row = idx >> 3;
            int q   = idx & 7;
            int grow = row0 + row;
            float4 v = make_float4(0.f, 0.f, 0.f, 0.f);
            if (grow < N)
                v = *(const float4*)&x[(size_t)grow * CIN + k0 + q * 4];
            xs[(q*4+0)*LDS_STRIDE + row] = v.x;
            xs[(q*4+1)*LDS_STRIDE + row] = v.y;
            xs[(q*4+2)*LDS_STRIDE + row] = v.z;
            xs[(q*4+3)*LDS_STRIDE + row] = v.w;
        }
        #pragma unroll
        for (int it = 0; it < 4; ++it) {
            int idx = it * 256 + t;
            int k   = idx >> 5;
            int q   = idx & 31;
            float4 v;
            if (q < 16) v = *(const float4*)&Wmu[(size_t)(k0 + k) * COUT + q * 4];
            else        v = *(const float4*)&Wls[(size_t)(k0 + k) * COUT + (q - 16) * 4];
            *(float4*)&wsl[k * LDS_STRIDE + q * 4] = v;
        }
        __syncthreads();

        #pragma unroll
        for (int k = 0; k < KCHUNK; ++k) {
            const float* xr = &xs [k * LDS_STRIDE + r0];
            const float* wr = &wsl[k * LDS_STRIDE + c0];
            float a[8], bb[8];
            *(float4*)&a[0]  = *(const float4*)&xr[0];
            *(float4*)&a[4]  = *(const float4*)&xr[4];
            *(float4*)&bb[0] = *(const float4*)&wr[0];
            *(float4*)&bb[4] = *(const float4*)&wr[4];
            #pragma unroll
            for (int i = 0; i < 8; ++i)
                #pragma unroll
                for (int j = 0; j < 8; ++j)
                    acc[i][j] = fmaf(a[i], bb[j], acc[i][j]);
        }
        __syncthreads();
    }

    #pragma unroll
    for (int i = 0; i < 8; ++i) {
        int grow = row0 + r0 + i;
        if (grow < N) {
            int degp1 = rowptr[grow + 1] - rowptr[grow] + 1;
            float dinv = rsqrtf((float)degp1);
            union { __half h[8]; uint4 u; } o;
            #pragma unroll
            for (int j = 0; j < 8; ++j)
                o.h[j] = __float2half(acc[i][j] * dinv);
            *(uint4*)&Hs[(size_t)grow * CCAT + c0] = o.u;
        }
    }
}

// ---------------- gather + finalize: one wave per node ---------------------
// lane l holds channels {2l, 2l+1} (fp16 pair) of the 128-wide concat
// (mu: lanes 0-31, ls: lanes 32-63); accumulate fp32, shfl_xor(32) to pair.
__global__ __launch_bounds__(256) void gather_finalize_kernel(
    const int*    __restrict__ rowptr,
    const int*    __restrict__ csr,
    const __half* __restrict__ Hs,
    const float*  __restrict__ bmu, const float* __restrict__ bls,
    const float*  __restrict__ eps,
    float* __restrict__ out, int N)
{
    const int t    = threadIdx.x;
    const int lane = t & 63;
    const int node = blockIdx.x * 4 + (t >> 6);
    if (node >= N) return;

    const __half2* Hs2 = (const __half2*)Hs;
    const int begin = rowptr[node];
    const int end   = rowptr[node + 1];

    // self-loop init
    float2 acc = __half22float2(Hs2[(size_t)node * 64 + lane]);

    for (int base = begin; base < end; base += 64) {
        int navail = end - base;
        if (navail > 64) navail = 64;
        int sv = (lane < navail) ? csr[base + lane] : 0;
        int j = 0;
        for (; j + 4 <= navail; j += 4) {
            int s0 = __shfl(sv, j,     64);
            int s1 = __shfl(sv, j + 1, 64);
            int s2 = __shfl(sv, j + 2, 64);
            int s3 = __shfl(sv, j + 3, 64);
            float2 v0 = __half22float2(Hs2[(size_t)s0 * 64 + lane]);
            float2 v1 = __half22float2(Hs2[(size_t)s1 * 64 + lane]);
            float2 v2 = __half22float2(Hs2[(size_t)s2 * 64 + lane]);
            float2 v3 = __half22float2(Hs2[(size_t)s3 * 64 + lane]);
            acc.x += (v0.x + v1.x) + (v2.x + v3.x);
            acc.y += (v0.y + v1.y) + (v2.y + v3.y);
        }
        for (; j < navail; ++j) {
            int s = __shfl(sv, j, 64);
            float2 v = __half22float2(Hs2[(size_t)s * 64 + lane]);
            acc.x += v.x;
            acc.y += v.y;
        }
    }

    float ox = __shfl_xor(acc.x, 32, 64);
    float oy = __shfl_xor(acc.y, 32, 64);

    if (lane < 32) {
        float dinv = rsqrtf((float)(end - begin + 1));
        const float2* bmu2 = (const float2*)bmu;
        const float2* bls2 = (const float2*)bls;
        float2 bm = bmu2[lane];
        float2 bl = bls2[lane];
        float2 e2 = ((const float2*)eps)[(size_t)node * 32 + lane];
        float mu0 = acc.x * dinv + bm.x;
        float mu1 = acc.y * dinv + bm.y;
        float ls0 = ox * dinv + bl.x;
        float ls1 = oy * dinv + bl.y;
        float2 z;
        z.x = mu0 + e2.x * expf(fminf(ls0, MAX_LOGSTD));
        z.y = mu1 + e2.y * expf(fminf(ls1, MAX_LOGSTD));
        ((float2*)out)[(size_t)node * 32 + lane] = z;
    }
}

extern "C" void kernel_launch(void* const* d_in, const int* in_sizes, int n_in,
                              void* d_out, int out_size, void* d_ws, size_t ws_size,
                              hipStream_t stream) {
    const float* x   = (const float*)d_in[0];
    const int*   ei  = (const int*)  d_in[1];   // [2, E] int32
    const float* Wmu = (const float*)d_in[2];
    const float* bmu = (const float*)d_in[3];
    const float* Wls = (const float*)d_in[4];
    const float* bls = (const float*)d_in[5];
    const float* eps = (const float*)d_in[6];

    const int E = in_sizes[1] / 2;
    const int N = in_sizes[6] / COUT;

    const int* src = ei;
    const int* dst = ei + E;

    const int NB    = (N + 127) >> BSHIFT;        // coarse buckets (<=1024)
    const int M     = NB * PART_G;                // histogram matrix size
    const int chunk = (E + PART_G - 1) / PART_G;  // edges per partition block

    // workspace carve-up (all 512B-aligned)
    char* ws = (char*)d_ws;
    size_t off = 0;
    auto carve = [&](size_t bytes) {
        char* p = ws + off;
        off = (off + bytes + 511) & ~(size_t)511;
        return p;
    };
    int*  bh     = (int*)carve((size_t)M * sizeof(int));
    int*  sc     = (int*)carve((size_t)M * sizeof(int));
    int*  bsums  = (int*)carve(256 * sizeof(int));
    int*  boffs  = (int*)carve(256 * sizeof(int));
    int*  rowptr = (int*)carve((size_t)(N + 1) * sizeof(int));
    int*  csr    = (int*)carve((size_t)E * sizeof(int));
    int2* pairs  = (int2*)carve((size_t)E * sizeof(int2));
    __half* Hs   = (__half*)carve((size_t)N * CCAT * sizeof(__half));

    const int nb = (M + 1023) / 1024;   // scan stage-1 blocks (<=256)

    hist_kernel<<<PART_G, 256, 0, stream>>>(dst, bh, E, NB, chunk);
    scan_block_kernel<<<nb, 256, 0, stream>>>(bh, sc, bsums, M);
    scan_top_kernel<<<1, 256, 0, stream>>>(bsums, boffs, nb);
    add_off_kernel<<<(M + 255) / 256, 256, 0, stream>>>(sc, boffs, M);
    partition_kernel<<<PART_G, 256, 0, stream>>>(src, dst, sc, pairs, E, NB, chunk);
    bucket_sort_kernel<<<NB, 256, 0, stream>>>(sc, pairs, csr, rowptr, E, NB, N);

    gemm_scale_kernel<<<(N + TILE_M - 1) / TILE_M, 256, 0, stream>>>(
        x, Wmu, Wls, rowptr, Hs, N);

    gather_finalize_kernel<<<(N + 3) / 4, 256, 0, stream>>>(
        rowptr, csr, Hs, bmu, bls, eps, (float*)d_out, N);
}